// Round 7
// baseline (342.166 us; speedup 1.0000x reference)
//
#include <hip/hip_runtime.h>

// BilateralSliceApply: grid [N,2,16,16,8] f32, guide [N,2048,2048] f32,
// input [N,3,2048,2048] f32 -> out [N,1,2048,2048] f32
// out = a*(x0+x1+x2)+b where (a,b) = trilinear slice of grid at
// (y=h/2047*15, x=w/2047*15, z=(guide+1)*0.5*7).

typedef float f32x4 __attribute__((ext_vector_type(4)));

namespace {
constexpr int N_IMG = 4;
constexpr int GH = 16, GW = 16, GD = 8;
constexpr int H = 2048, W = 2048;
constexpr int P = H * W;             // pixels per image
constexpr int SP = GH * GW * GD;     // 2048 grid cells per channel
constexpr int BX = 512;              // blocks per image
constexpr int TPB = 256;
constexpr int PXT = 8;               // pixels per thread per iteration (2x f32x4)
constexpr int STRIDE = BX * TPB * PXT;  // 1048576 = 512 rows -> wb invariant
constexpr int ITERS = P / STRIDE;       // 4 (exact)
constexpr float XSC = 15.0f / 2047.0f;
}

__global__ __launch_bounds__(TPB) void bsa_kernel(
    const float* __restrict__ grid,   // [N,2,GH,GW,GD]
    const float* __restrict__ guide,  // [N,H,W]
    const float* __restrict__ input,  // [N,3,H,W]
    float* __restrict__ out)          // [N,H,W]
{
    // LDS: [y][x][z] of float2 {a,b}; +1 zeroed pad so z0+1 is always readable
    // (its weight is exactly 0 when z0==GD-1).
    __shared__ float2 L[SP + 1];
    const int n = blockIdx.y;
    const int tid = threadIdx.x;

    const float* gsrc = grid + (size_t)n * (2 * SP);
#pragma unroll
    for (int k = 0; k < SP / TPB; ++k) {
        const int i = tid + k * TPB;                    // y*128 + x*8 + z
        L[i] = make_float2(gsrc[i], gsrc[SP + i]);      // {a, b}
    }
    if (tid == 0) L[SP] = make_float2(0.0f, 0.0f);
    __syncthreads();

    const float* __restrict__ gu  = guide + (size_t)n * P;
    const float* __restrict__ in0 = input + (size_t)n * 3 * P;
    const float* __restrict__ in1 = in0 + P;
    const float* __restrict__ in2 = in1 + P;
    float*       __restrict__ op  = out + (size_t)n * P;

    const int base = (blockIdx.x * TPB + tid) * PXT;
    const int wb   = base & (W - 1);   // constant across iterations

    // Hoisted x-interpolation (wb is loop-invariant; ix in [0,15]).
    float wx0h[PXT], wx1h[PXT];
    int   xb0h[PXT], xb1h[PXT];
#pragma unroll
    for (int j = 0; j < PXT; ++j) {
        const float ix  = (float)(wb + j) * XSC;
        const float fxf = floorf(ix);
        const float fx  = ix - fxf;
        int x0 = (int)fxf; if (x0 > GW - 1) x0 = GW - 1;
        const int x1 = (x0 + 1 > GW - 1) ? GW - 1 : x0 + 1;
        wx0h[j] = 1.0f - fx; wx1h[j] = fx;
        xb0h[j] = x0 * GD;   xb1h[j] = x1 * GD;
    }

#pragma unroll
    for (int it = 0; it < ITERS; ++it) {
        const int p = base + it * STRIDE;
        const int h = p >> 11;           // row (W = 2048)

        // 8 independent 16B loads in flight per iteration.
        const f32x4 gA = __builtin_nontemporal_load((const f32x4*)(gu  + p));
        const f32x4 gB = __builtin_nontemporal_load((const f32x4*)(gu  + p + 4));
        const f32x4 aA = __builtin_nontemporal_load((const f32x4*)(in0 + p));
        const f32x4 aB = __builtin_nontemporal_load((const f32x4*)(in0 + p + 4));
        const f32x4 bA = __builtin_nontemporal_load((const f32x4*)(in1 + p));
        const f32x4 bB = __builtin_nontemporal_load((const f32x4*)(in1 + p + 4));
        const f32x4 cA = __builtin_nontemporal_load((const f32x4*)(in2 + p));
        const f32x4 cB = __builtin_nontemporal_load((const f32x4*)(in2 + p + 4));

        // y interpolation (shared by the 8 pixels)
        const float iy  = (float)h * XSC;
        const float fyf = floorf(iy);
        const float fy  = iy - fyf;
        int y0 = (int)fyf; if (y0 > GH - 1) y0 = GH - 1;
        const int y1 = (y0 + 1 > GH - 1) ? GH - 1 : y0 + 1;
        const float wy0 = 1.0f - fy, wy1 = fy;
        const int yb0 = y0 * (GW * GD), yb1 = y1 * (GW * GD);

        float rr[PXT];
#pragma unroll
        for (int j = 0; j < PXT; ++j) {
            const float gval = (j < 4) ? gA[j] : gB[j - 4];
            const float xs   = (j < 4) ? ((aA[j] + bA[j]) + cA[j])
                                       : ((aB[j - 4] + bB[j - 4]) + cB[j - 4]);

            // z interpolation: guide in [0,1) -> iz in [3.5,7)
            const float iz  = fmaf(gval, 3.5f, 3.5f);
            const float fzf = floorf(iz);
            const float fz  = iz - fzf;
            const int   z0  = (int)fzf;
            const float wz0 = 1.0f - fz, wz1 = fz;

            const int b00 = yb0 + xb0h[j] + z0;
            const int b01 = yb0 + xb1h[j] + z0;
            const int b10 = yb1 + xb0h[j] + z0;
            const int b11 = yb1 + xb1h[j] + z0;
            // adjacent pairs -> ds_read2_b64 candidates
            const float2 p00 = L[b00], q00 = L[b00 + 1];
            const float2 p01 = L[b01], q01 = L[b01 + 1];
            const float2 p10 = L[b10], q10 = L[b10 + 1];
            const float2 p11 = L[b11], q11 = L[b11 + 1];

            const float w00 = wy0 * wx0h[j], w01 = wy0 * wx1h[j];
            const float w10 = wy1 * wx0h[j], w11 = wy1 * wx1h[j];

            float a = w00 * fmaf(wz0, p00.x, wz1 * q00.x);
            a = fmaf(w01, fmaf(wz0, p01.x, wz1 * q01.x), a);
            a = fmaf(w10, fmaf(wz0, p10.x, wz1 * q10.x), a);
            a = fmaf(w11, fmaf(wz0, p11.x, wz1 * q11.x), a);
            float b = w00 * fmaf(wz0, p00.y, wz1 * q00.y);
            b = fmaf(w01, fmaf(wz0, p01.y, wz1 * q01.y), b);
            b = fmaf(w10, fmaf(wz0, p10.y, wz1 * q10.y), b);
            b = fmaf(w11, fmaf(wz0, p11.y, wz1 * q11.y), b);

            rr[j] = fmaf(a, xs, b);
        }

        const f32x4 r0 = {rr[0], rr[1], rr[2], rr[3]};
        const f32x4 r1 = {rr[4], rr[5], rr[6], rr[7]};
        __builtin_nontemporal_store(r0, (f32x4*)(op + p));
        __builtin_nontemporal_store(r1, (f32x4*)(op + p + 4));
    }
}

extern "C" void kernel_launch(void* const* d_in, const int* in_sizes, int n_in,
                              void* d_out, int out_size, void* d_ws, size_t ws_size,
                              hipStream_t stream) {
    const float* grid  = (const float*)d_in[0];   // [4,2,16,16,8]
    const float* guide = (const float*)d_in[1];   // [4,2048,2048]
    const float* input = (const float*)d_in[2];   // [4,3,2048,2048]
    float* out = (float*)d_out;                   // [4,1,2048,2048]

    dim3 grd(BX, N_IMG);
    dim3 blk(TPB);
    bsa_kernel<<<grd, blk, 0, stream>>>(grid, guide, input, out);
}

// Round 10
// 317.632 us; speedup vs baseline: 1.0772x; 1.0772x over previous
//
#include <hip/hip_runtime.h>

// BilateralSliceApply: grid [N,2,16,16,8] f32, guide [N,2048,2048] f32,
// input [N,3,2048,2048] f32 -> out [N,1,2048,2048] f32
// out = a*(x0+x1+x2)+b where (a,b) = trilinear slice of grid at
// (y=h/2047*15, x=w/2047*15, z=(guide+1)*0.5*7).

typedef float f32x4 __attribute__((ext_vector_type(4)));

namespace {
constexpr int N_IMG = 4;
constexpr int GH = 16, GW = 16, GD = 8;
constexpr int H = 2048, W = 2048;
constexpr int P = H * W;             // pixels per image
constexpr int SP = GH * GW * GD;     // 2048 grid cells per channel
constexpr int BX = 512;              // blocks per image
constexpr int TPB = 256;
constexpr int PXT = 4;               // pixels per thread per iteration
constexpr int STRIDE = BX * TPB * PXT;  // 524288 = 256 rows -> wb invariant
constexpr int ITERS = P / STRIDE;       // 8 (exact)
constexpr float XSC = 15.0f / 2047.0f;
}

__global__ __launch_bounds__(TPB) void bsa_kernel(
    const float* __restrict__ grid,   // [N,2,GH,GW,GD]
    const float* __restrict__ guide,  // [N,H,W]
    const float* __restrict__ input,  // [N,3,H,W]
    float* __restrict__ out)          // [N,H,W]
{
    // LDS: [y][x][z] of float2 {a,b}; +1 zeroed pad so z1=z0+1 can be read
    // unconditionally (its weight is 0 whenever it would be out of range).
    __shared__ float2 L[SP + 1];
    const int n = blockIdx.y;
    const int tid = threadIdx.x;

    const float* gsrc = grid + (size_t)n * (2 * SP);
#pragma unroll
    for (int k = 0; k < SP / TPB; ++k) {
        const int i = tid + k * TPB;                    // y*128 + x*8 + z
        L[i] = make_float2(gsrc[i], gsrc[SP + i]);      // {a, b}
    }
    if (tid == 0) L[SP] = make_float2(0.0f, 0.0f);
    __syncthreads();

    const float* __restrict__ gu  = guide + (size_t)n * P;
    const float* __restrict__ in0 = input + (size_t)n * 3 * P;
    const float* __restrict__ in1 = in0 + P;
    const float* __restrict__ in2 = in1 + P;
    float*       __restrict__ op  = out + (size_t)n * P;

    const int base = (blockIdx.x * TPB + tid) * PXT;
    const int wb   = base & (W - 1);   // constant across iterations

    // Hoisted x-interpolation (wb is loop-invariant).
    float wx0h[PXT], wx1h[PXT];
    int   xb0h[PXT], xb1h[PXT];
#pragma unroll
    for (int j = 0; j < PXT; ++j) {
        const float ix  = (float)(wb + j) * XSC;
        const float fxf = floorf(ix);
        const float fx  = ix - fxf;
        int x0 = (int)fxf; if (x0 > GW - 1) x0 = GW - 1;
        const int x1 = (x0 + 1 > GW - 1) ? GW - 1 : x0 + 1;
        wx0h[j] = 1.0f - fx; wx1h[j] = fx;
        xb0h[j] = x0 * GD;   xb1h[j] = x1 * GD;
    }

    // Depth-1 software pipeline: loads for it+1 issue before compute of it.
    int p = base;
    f32x4 gv = __builtin_nontemporal_load((const f32x4*)(gu  + p));
    f32x4 c0 = __builtin_nontemporal_load((const f32x4*)(in0 + p));
    f32x4 c1 = __builtin_nontemporal_load((const f32x4*)(in1 + p));
    f32x4 c2 = __builtin_nontemporal_load((const f32x4*)(in2 + p));

#pragma unroll
    for (int it = 0; it < ITERS; ++it) {
        const int pn = p + STRIDE;
        f32x4 gvn, c0n, c1n, c2n;
        if (it + 1 < ITERS) {
            gvn = __builtin_nontemporal_load((const f32x4*)(gu  + pn));
            c0n = __builtin_nontemporal_load((const f32x4*)(in0 + pn));
            c1n = __builtin_nontemporal_load((const f32x4*)(in1 + pn));
            c2n = __builtin_nontemporal_load((const f32x4*)(in2 + pn));
        }

        const int h = p >> 11;           // row (W = 2048)

        // y interpolation (shared by the 4 pixels)
        const float iy  = (float)h * XSC;
        const float fyf = floorf(iy);
        const float fy  = iy - fyf;
        int y0 = (int)fyf; if (y0 > GH - 1) y0 = GH - 1;
        const int y1 = (y0 + 1 > GH - 1) ? GH - 1 : y0 + 1;
        const float wy0 = 1.0f - fy, wy1 = fy;
        const int yb0 = y0 * (GW * GD), yb1 = y1 * (GW * GD);

        float rr[PXT];
#pragma unroll
        for (int j = 0; j < PXT; ++j) {
            // z interpolation from guide: guide in [0,1) -> iz in [3.5,7]
            const float iz  = fmaf(gv[j], 3.5f, 3.5f);
            const float fzf = floorf(iz);
            const float fz  = iz - fzf;
            const int   z0  = (int)fzf;           // 3..7; z0==7 => fz==0
            const float wz0 = 1.0f - fz, wz1 = fz;

            const int b00 = yb0 + xb0h[j] + z0;
            const int b01 = yb0 + xb1h[j] + z0;
            const int b10 = yb1 + xb0h[j] + z0;
            const int b11 = yb1 + xb1h[j] + z0;
            // adjacent pairs -> ds_read2_b64
            const float2 p00 = L[b00], q00 = L[b00 + 1];
            const float2 p01 = L[b01], q01 = L[b01 + 1];
            const float2 p10 = L[b10], q10 = L[b10 + 1];
            const float2 p11 = L[b11], q11 = L[b11 + 1];

            const float w00 = wy0 * wx0h[j], w01 = wy0 * wx1h[j];
            const float w10 = wy1 * wx0h[j], w11 = wy1 * wx1h[j];

            float a = w00 * fmaf(wz0, p00.x, wz1 * q00.x);
            a = fmaf(w01, fmaf(wz0, p01.x, wz1 * q01.x), a);
            a = fmaf(w10, fmaf(wz0, p10.x, wz1 * q10.x), a);
            a = fmaf(w11, fmaf(wz0, p11.x, wz1 * q11.x), a);
            float b = w00 * fmaf(wz0, p00.y, wz1 * q00.y);
            b = fmaf(w01, fmaf(wz0, p01.y, wz1 * q01.y), b);
            b = fmaf(w10, fmaf(wz0, p10.y, wz1 * q10.y), b);
            b = fmaf(w11, fmaf(wz0, p11.y, wz1 * q11.y), b);

            rr[j] = fmaf(a, (c0[j] + c1[j]) + c2[j], b);
        }

        const f32x4 res = {rr[0], rr[1], rr[2], rr[3]};
        __builtin_nontemporal_store(res, (f32x4*)(op + p));

        p = pn; gv = gvn; c0 = c0n; c1 = c1n; c2 = c2n;
    }
}

extern "C" void kernel_launch(void* const* d_in, const int* in_sizes, int n_in,
                              void* d_out, int out_size, void* d_ws, size_t ws_size,
                              hipStream_t stream) {
    const float* grid  = (const float*)d_in[0];   // [4,2,16,16,8]
    const float* guide = (const float*)d_in[1];   // [4,2048,2048]
    const float* input = (const float*)d_in[2];   // [4,3,2048,2048]
    float* out = (float*)d_out;                   // [4,1,2048,2048]

    dim3 grd(BX, N_IMG);
    dim3 blk(TPB);
    bsa_kernel<<<grd, blk, 0, stream>>>(grid, guide, input, out);
}